// Round 2
// baseline (120.176 us; speedup 1.0000x reference)
//
#include <hip/hip_runtime.h>

// CensusLoss: mean over B,H,W and 49 taps of sqrt(d^2 + eps), where
// d = h[neighbor (zero-padded)] - h[center], h = gray(pred) - gray(gt).
// B=8, C=3, H=W=512 fixed by setup_inputs.

#define BB  8
#define HH  512
#define WW  512
#define HWP (HH * WW)
#define PAD 3
#define TW  64
#define TH  16
#define LW  (TW + 2 * PAD)   // 70
#define LH  (TH + 2 * PAD)   // 22
#define EPSF 1e-6f

__global__ __launch_bounds__(256, 4)
void census_loss_kernel(const float* __restrict__ pred,
                        const float* __restrict__ gt,
                        float* __restrict__ out) {
    __shared__ float sh[LH * LW];

    const int tid = threadIdx.x;
    const int bx = blockIdx.x;   // tile x: 0..7
    const int by = blockIdx.y;   // tile y: 0..31
    const int b  = blockIdx.z;   // batch: 0..7

    const float* pr = pred + (size_t)b * 3 * HWP;
    const float* gr = gt   + (size_t)b * 3 * HWP;

    const int gx0 = bx * TW - PAD;
    const int gy0 = by * TH - PAD;

    // Stage grayscale-diff tile + halo into LDS, zero-filled out of bounds
    // (matches reference's zero padding: h_padded = 0 outside the image).
    for (int i = tid; i < LH * LW; i += 256) {
        const int ly = i / LW;
        const int lx = i - ly * LW;
        const int gy = gy0 + ly;
        const int gx = gx0 + lx;
        float v = 0.f;
        if ((unsigned)gy < (unsigned)HH && (unsigned)gx < (unsigned)WW) {
            const int o = gy * WW + gx;
            v = 0.299f * (pr[o]           - gr[o])
              + 0.587f * (pr[o + HWP]     - gr[o + HWP])
              + 0.114f * (pr[o + 2 * HWP] - gr[o + 2 * HWP]);
        }
        sh[i] = v;
    }
    __syncthreads();

    // Each thread: 4 vertically adjacent pixels at (ly0..ly0+3, lx).
    const int lx  = tid & 63;
    const int ly0 = (tid >> 6) * 4;

    float c[4];
#pragma unroll
    for (int p = 0; p < 4; ++p)
        c[p] = sh[(PAD + ly0 + p) * LW + PAD + lx];

    float acc = 0.f;
#pragma unroll
    for (int dx = 0; dx < 7; ++dx) {
        // 10-row column strip covers all four pixels' 7-tap windows.
        float s[10];
#pragma unroll
        for (int k = 0; k < 10; ++k)
            s[k] = sh[(ly0 + k) * LW + lx + dx];
#pragma unroll
        for (int p = 0; p < 4; ++p) {
#pragma unroll
            for (int k = 0; k < 7; ++k) {
                const float d = s[p + k] - c[p];
                acc += __builtin_amdgcn_sqrtf(fmaf(d, d, EPSF));
            }
        }
    }

    // Wave (64-lane) butterfly reduce, then cross-wave via LDS.
#pragma unroll
    for (int off = 32; off > 0; off >>= 1)
        acc += __shfl_down(acc, off);

    __shared__ float wsum[4];
    if ((tid & 63) == 0) wsum[tid >> 6] = acc;
    __syncthreads();
    if (tid == 0) {
        const float s = (wsum[0] + wsum[1]) + (wsum[2] + wsum[3]);
        const float scale = (float)(1.0 / ((double)BB * 49.0 * HH * WW));
        atomicAdd(out, s * scale);
    }
}

extern "C" void kernel_launch(void* const* d_in, const int* in_sizes, int n_in,
                              void* d_out, int out_size, void* d_ws, size_t ws_size,
                              hipStream_t stream) {
    const float* pred = (const float*)d_in[0];
    const float* gt   = (const float*)d_in[1];
    float* out = (float*)d_out;

    // d_out is poisoned with 0xAA before every launch; we accumulate into it.
    hipMemsetAsync(out, 0, sizeof(float), stream);

    dim3 grid(WW / TW, HH / TH, BB);   // 8 x 32 x 8 = 2048 blocks
    census_loss_kernel<<<grid, 256, 0, stream>>>(pred, gt, out);
}

// Round 4
// 107.891 us; speedup vs baseline: 1.1139x; 1.1139x over previous
//
#include <hip/hip_runtime.h>

// CensusLoss = mean over B,H,W and 49 taps of sqrt(d^2+eps),
// d = h[neighbor (zero-padded)] - h[center], h = gray(pred) - gray(gt).
// Two-pass: A) h-plane precompute (streaming), B) 7x7 stencil + reduce.

#define BB  8
#define HH  512
#define WW  512
#define HWP (HH * WW)
#define EPSF 1e-6f

// ---------------- Kernel A: h = gray(pred - gt), float4 streaming ----------
__global__ __launch_bounds__(256)
void gray_diff_kernel(const float* __restrict__ pred,
                      const float* __restrict__ gt,
                      float* __restrict__ h) {
    const int t = blockIdx.x * 256 + threadIdx.x;     // 0 .. 524287
    const int b = t >> 16;                            // HWP/4 = 65536 float4s
    const int q = (t & 65535) << 2;                   // pixel offset in plane
    const float* pb = pred + (size_t)b * 3 * HWP + q;
    const float* gb = gt   + (size_t)b * 3 * HWP + q;
    const float4 pr = *(const float4*)(pb);
    const float4 pg = *(const float4*)(pb + HWP);
    const float4 pbl = *(const float4*)(pb + 2 * HWP);
    const float4 gr = *(const float4*)(gb);
    const float4 gg = *(const float4*)(gb + HWP);
    const float4 gbl = *(const float4*)(gb + 2 * HWP);
    float4 o;
    o.x = 0.299f * (pr.x - gr.x) + 0.587f * (pg.x - gg.x) + 0.114f * (pbl.x - gbl.x);
    o.y = 0.299f * (pr.y - gr.y) + 0.587f * (pg.y - gg.y) + 0.114f * (pbl.y - gbl.y);
    o.z = 0.299f * (pr.z - gr.z) + 0.587f * (pg.z - gg.z) + 0.114f * (pbl.z - gbl.z);
    o.w = 0.299f * (pr.w - gr.w) + 0.587f * (pg.w - gg.w) + 0.114f * (pbl.w - gbl.w);
    *(float4*)(h + (size_t)b * HWP + q) = o;
}

// ---------------- Kernel B: 7x7 Charbonnier stencil + global reduce --------
#define TW  64
#define TH  32
#define PAD 3
#define LW2 (TW + 2 * PAD)   // 70
#define LH2 (TH + 2 * PAD)   // 38

__global__ __launch_bounds__(256)
void census_stencil_kernel(const float* __restrict__ h,
                           float* __restrict__ out) {
    __shared__ float sh[LH2 * LW2];

    const int tid = threadIdx.x;
    const int bx = blockIdx.x;     // 0..7
    const int by = blockIdx.y;     // 0..15
    const int b  = blockIdx.z;     // 0..7

    const float* hp = h + (size_t)b * HWP;
    const int gx0 = bx * TW - PAD;
    const int gy0 = by * TH - PAD;

    for (int i = tid; i < LH2 * LW2; i += 256) {
        const int ly = i / LW2;
        const int lx = i - ly * LW2;
        const int gy = gy0 + ly;
        const int gx = gx0 + lx;
        float v = 0.f;
        if ((unsigned)gy < (unsigned)HH && (unsigned)gx < (unsigned)WW)
            v = hp[gy * WW + gx];
        sh[i] = v;
    }
    __syncthreads();

    // 4 waves x 64 lanes: lane = column, wave owns 8 consecutive rows.
    const int lx  = tid & 63;
    const int ly0 = (tid >> 6) * 8;

    float c[8];
#pragma unroll
    for (int p = 0; p < 8; ++p)
        c[p] = sh[(PAD + ly0 + p) * LW2 + PAD + lx];

    float acc = 0.f;
#pragma unroll
    for (int dx = 0; dx < 7; ++dx) {
        float s[14];                       // 14-row strip covers 8 pixels' 7 taps
#pragma unroll
        for (int k = 0; k < 14; ++k)
            s[k] = sh[(ly0 + k) * LW2 + lx + dx];
#pragma unroll
        for (int p = 0; p < 8; ++p) {
#pragma unroll
            for (int k = 0; k < 7; ++k) {
                const float d = s[p + k] - c[p];
                acc += __builtin_amdgcn_sqrtf(fmaf(d, d, EPSF));
            }
        }
    }

#pragma unroll
    for (int off = 32; off > 0; off >>= 1)
        acc += __shfl_down(acc, off);

    __shared__ float wsum[4];
    if ((tid & 63) == 0) wsum[tid >> 6] = acc;
    __syncthreads();
    if (tid == 0) {
        const float s = (wsum[0] + wsum[1]) + (wsum[2] + wsum[3]);
        const float scale = (float)(1.0 / ((double)BB * 49.0 * HH * WW));
        atomicAdd(out, s * scale);
    }
}

// ---------------- Fallback: round-2 verified fused kernel ------------------
#define FTW 64
#define FTH 16
#define FLW (FTW + 2 * PAD)
#define FLH (FTH + 2 * PAD)

__global__ __launch_bounds__(256, 4)
void census_loss_fused_kernel(const float* __restrict__ pred,
                              const float* __restrict__ gt,
                              float* __restrict__ out) {
    __shared__ float sh[FLH * FLW];
    const int tid = threadIdx.x;
    const int bx = blockIdx.x, by = blockIdx.y, b = blockIdx.z;
    const float* pr = pred + (size_t)b * 3 * HWP;
    const float* gr = gt   + (size_t)b * 3 * HWP;
    const int gx0 = bx * FTW - PAD;
    const int gy0 = by * FTH - PAD;
    for (int i = tid; i < FLH * FLW; i += 256) {
        const int ly = i / FLW;
        const int lx = i - ly * FLW;
        const int gy = gy0 + ly, gx = gx0 + lx;
        float v = 0.f;
        if ((unsigned)gy < (unsigned)HH && (unsigned)gx < (unsigned)WW) {
            const int o = gy * WW + gx;
            v = 0.299f * (pr[o] - gr[o]) + 0.587f * (pr[o + HWP] - gr[o + HWP])
              + 0.114f * (pr[o + 2 * HWP] - gr[o + 2 * HWP]);
        }
        sh[i] = v;
    }
    __syncthreads();
    const int lx = tid & 63;
    const int ly0 = (tid >> 6) * 4;
    float c[4];
#pragma unroll
    for (int p = 0; p < 4; ++p) c[p] = sh[(PAD + ly0 + p) * FLW + PAD + lx];
    float acc = 0.f;
#pragma unroll
    for (int dx = 0; dx < 7; ++dx) {
        float s[10];
#pragma unroll
        for (int k = 0; k < 10; ++k) s[k] = sh[(ly0 + k) * FLW + lx + dx];
#pragma unroll
        for (int p = 0; p < 4; ++p)
#pragma unroll
            for (int k = 0; k < 7; ++k) {
                const float d = s[p + k] - c[p];
                acc += __builtin_amdgcn_sqrtf(fmaf(d, d, EPSF));
            }
    }
#pragma unroll
    for (int off = 32; off > 0; off >>= 1) acc += __shfl_down(acc, off);
    __shared__ float wsum[4];
    if ((tid & 63) == 0) wsum[tid >> 6] = acc;
    __syncthreads();
    if (tid == 0) {
        const float s = (wsum[0] + wsum[1]) + (wsum[2] + wsum[3]);
        const float scale = (float)(1.0 / ((double)BB * 49.0 * HH * WW));
        atomicAdd(out, s * scale);
    }
}

extern "C" void kernel_launch(void* const* d_in, const int* in_sizes, int n_in,
                              void* d_out, int out_size, void* d_ws, size_t ws_size,
                              hipStream_t stream) {
    const float* pred = (const float*)d_in[0];
    const float* gt   = (const float*)d_in[1];
    float* out = (float*)d_out;

    hipMemsetAsync(out, 0, sizeof(float), stream);

    const size_t h_bytes = (size_t)BB * HWP * sizeof(float);
    if (ws_size >= h_bytes) {
        float* hbuf = (float*)d_ws;
        gray_diff_kernel<<<dim3(2048), 256, 0, stream>>>(pred, gt, hbuf);
        census_stencil_kernel<<<dim3(WW / TW, HH / TH, BB), 256, 0, stream>>>(hbuf, out);
    } else {
        census_loss_fused_kernel<<<dim3(WW / FTW, HH / FTH, BB), 256, 0, stream>>>(pred, gt, out);
    }
}

// Round 5
// 103.652 us; speedup vs baseline: 1.1594x; 1.0409x over previous
//
#include <hip/hip_runtime.h>

// CensusLoss = mean over B,H,W and 49 taps of sqrt(d^2+eps),
// d = h[neighbor (zero-padded)] - h[center], h = gray(pred) - gray(gt).
//
// Single fused kernel using the evenness of f(d)=sqrt(d^2+eps):
//   S = N*f(0) + sum_{delta in H} [ 2*sum_{x: x+delta in} f(h[x+delta]-h[x])
//                                   + sum_{x: x+delta out} f(h[x])
//                                   + sum_{x: x-delta out} f(h[x]) ]
// where H = {dy in 1..3, dx in -3..3} u {dy=0, dx in 1..3}  (24 offsets).
// With zero-padded LDS we accumulate f(h~[x+d]-h[x]) per half-offset, double
// it, and add the exact boundary weight w(y,x)*f(h[x]) (nonzero only within
// 3 px of an image edge; applied only in edge blocks).

#define BB  8
#define HH  512
#define WW  512
#define HWP (HH * WW)
#define EPSF 1e-6f
#define PAD 3
#define TW  64
#define TH  32
#define LW  72               // float4-aligned staging width: [bx*64-4, bx*64+68)
#define LHR (TH + 2 * PAD)   // 38 rows
#define NU  (LHR * (LW / 4)) // 684 float4 staging units

__global__ __launch_bounds__(256)
void census_fused_kernel(const float* __restrict__ pred,
                         const float* __restrict__ gt,
                         float* __restrict__ out) {
    __shared__ float sh[LHR * LW];   // 10944 B

    const int tid = threadIdx.x;
    const int bx = blockIdx.x;   // 0..7
    const int by = blockIdx.y;   // 0..15
    const int b  = blockIdx.z;   // 0..7

    const float* pr = pred + (size_t)b * 3 * HWP;
    const float* gr = gt   + (size_t)b * 3 * HWP;

    const int gx0 = bx * TW - 4;    // global x of LDS col 0 (multiple of 4)
    const int gy0 = by * TH - PAD;  // global y of LDS row 0

    // Stage grayscale-diff tile+halo. Each 16B unit is fully in- or out-of-
    // bounds (512 % 4 == 0 and gx0 % 4 == 0); OOB units stage 0 (zero pad).
    for (int i = tid; i < NU; i += 256) {
        const int r = i / (LW / 4);
        const int j = i - r * (LW / 4);
        const int gy = gy0 + r;
        const int gx = gx0 + 4 * j;
        float4 o = make_float4(0.f, 0.f, 0.f, 0.f);
        if ((unsigned)gy < (unsigned)HH && (unsigned)gx < (unsigned)WW) {
            const int off = gy * WW + gx;
            const float4 p0 = *(const float4*)(pr + off);
            const float4 p1 = *(const float4*)(pr + off + HWP);
            const float4 p2 = *(const float4*)(pr + off + 2 * HWP);
            const float4 g0 = *(const float4*)(gr + off);
            const float4 g1 = *(const float4*)(gr + off + HWP);
            const float4 g2 = *(const float4*)(gr + off + 2 * HWP);
            o.x = 0.299f * (p0.x - g0.x) + 0.587f * (p1.x - g1.x) + 0.114f * (p2.x - g2.x);
            o.y = 0.299f * (p0.y - g0.y) + 0.587f * (p1.y - g1.y) + 0.114f * (p2.y - g2.y);
            o.z = 0.299f * (p0.z - g0.z) + 0.587f * (p1.z - g1.z) + 0.114f * (p2.z - g2.z);
            o.w = 0.299f * (p0.w - g0.w) + 0.587f * (p1.w - g1.w) + 0.114f * (p2.w - g2.w);
        }
        *(float4*)(&sh[r * LW + 4 * j]) = o;
    }
    __syncthreads();

    // 4 waves x 64 lanes: lane = tile column, wave owns 8 consecutive rows.
    const int lx  = tid & 63;
    const int ly0 = (tid >> 6) * 8;

    float c[8];
#pragma unroll
    for (int p = 0; p < 8; ++p)
        c[p] = sh[(ly0 + PAD + p) * LW + (lx + 4)];

    // Half-space offsets: dx<=0 -> dy in 1..3; dx>0 -> dy in 0..3. (24 total)
    float acc2 = 0.f;
#pragma unroll
    for (int dx = -3; dx <= 3; ++dx) {
        const int col = lx + 4 + dx;
        float s[11];
#pragma unroll
        for (int k = 0; k < 11; ++k)
            s[k] = sh[(ly0 + PAD + k) * LW + col];
        const int dy0 = (dx > 0) ? 0 : 1;
#pragma unroll
        for (int p = 0; p < 8; ++p) {
#pragma unroll
            for (int dy = dy0; dy <= 3; ++dy) {
                const float d = s[p + dy] - c[p];
                acc2 += __builtin_amdgcn_sqrtf(fmaf(d, d, EPSF));
            }
        }
    }

    // Boundary correction: weight w = b*(a-a') + max(0,3-x) - max(0,x-508),
    // a = min(3, 511-y), a' = min(3, y), b = min(3,x)+min(3,511-x)+1.
    // Zero for pixels >=3 px from every edge -> only edge blocks evaluate it.
    float corr = 0.f;
    if (bx == 0 || bx == (WW / TW - 1) || by == 0 || by == (HH / TH - 1)) {
        const int xx = bx * TW + lx;
        const int bw = min(3, xx) + min(3, WW - 1 - xx) + 1;
        const int e  = max(0, 3 - xx) - max(0, xx - (WW - 4));
#pragma unroll
        for (int p = 0; p < 8; ++p) {
            const int y  = by * TH + ly0 + p;
            const int a  = min(3, HH - 1 - y);
            const int ap = min(3, y);
            const int w  = bw * (a - ap) + e;
            if (w != 0)
                corr += (float)w * __builtin_amdgcn_sqrtf(fmaf(c[p], c[p], EPSF));
        }
    }

    float acc = fmaf(2.f, acc2, corr);

#pragma unroll
    for (int off = 32; off > 0; off >>= 1)
        acc += __shfl_down(acc, off);

    __shared__ float wsum[4];
    if ((tid & 63) == 0) wsum[tid >> 6] = acc;
    __syncthreads();
    if (tid == 0) {
        // Per-block share of the center-tap term: TW*TH * f(0), f(0)=sqrt(eps).
        const float s = (wsum[0] + wsum[1]) + (wsum[2] + wsum[3])
                      + (float)(TW * TH) * __builtin_amdgcn_sqrtf(EPSF);
        const float scale = (float)(1.0 / ((double)BB * 49.0 * HH * WW));
        atomicAdd(out, s * scale);
    }
}

extern "C" void kernel_launch(void* const* d_in, const int* in_sizes, int n_in,
                              void* d_out, int out_size, void* d_ws, size_t ws_size,
                              hipStream_t stream) {
    const float* pred = (const float*)d_in[0];
    const float* gt   = (const float*)d_in[1];
    float* out = (float*)d_out;

    // d_out is poisoned with 0xAA before every launch; we accumulate into it.
    hipMemsetAsync(out, 0, sizeof(float), stream);

    census_fused_kernel<<<dim3(WW / TW, HH / TH, BB), 256, 0, stream>>>(pred, gt, out);
}